// Round 1
// baseline (116.204 us; speedup 1.0000x reference)
//
#include <hip/hip_runtime.h>
#include <math.h>

// Problem constants
#define BATCH 256
#define KSNIP 32
#define CH    2048
#define CH4   512   // CH/4
#define NCLSS 20

// workspace offsets (floats)
#define OFF_DOTNAPB 0        // [256*32] dot(meanNA[b], PB[b,k,:])
#define OFF_SQPB    8192     // [256*32] ||PB[b,k,:]||^2
#define OFF_DOTNBPA 16384    // [256*32] dot(meanNB[b], PA[b,k,:])
#define OFF_SQPA    24576    // [256*32] ||PA[b,k,:]||^2
#define OFF_ACT     32768    // [256*32] PA[b,k,:].mean()
#define OFF_N2PA    40960    // [256] ||meanPA||^2
#define OFF_N2PB    41216
#define OFF_N2NA    41472
#define OFF_N2NB    41728
#define OFF_DAP     41984    // [256] dot(meanNA, meanPA)
#define OFF_DBP     42240    // [256] dot(meanNB, meanPB)

__device__ __forceinline__ float dot4(float4 a, float4 b) {
    return a.x*b.x + a.y*b.y + a.z*b.z + a.w*b.w;
}
__device__ __forceinline__ float sum4(float4 a) { return a.x + a.y + a.z + a.w; }

// One block per video b. 512 threads; thread owns float4 column c4 = tid.
__global__ __launch_bounds__(512) void per_video_kernel(
    const float* __restrict__ PA, const float* __restrict__ PB,
    const float* __restrict__ NAp, const float* __restrict__ NBp,
    float* __restrict__ ws)
{
    const int b    = blockIdx.x;
    const int tid  = threadIdx.x;
    const int wave = tid >> 6;
    const int lane = tid & 63;

    __shared__ float4 mNA4[CH4];
    __shared__ float4 mNB4[CH4];
    __shared__ float4 mPA4[CH4];
    __shared__ float4 mPB4[CH4];
    __shared__ float  sp[5][KSNIP][8];   // per-k, per-wave partials
    __shared__ float  sred[8][6];

    const float4* PA4 = (const float4*)(PA  + (size_t)b * KSNIP * CH);
    const float4* PB4 = (const float4*)(PB  + (size_t)b * KSNIP * CH);
    const float4* NA4 = (const float4*)(NAp + (size_t)b * KSNIP * CH);
    const float4* NB4 = (const float4*)(NBp + (size_t)b * KSNIP * CH);

    // ---- phase 1: means of NA, NB over K ----
    {
        float4 aN = {0.f,0.f,0.f,0.f}, bN = {0.f,0.f,0.f,0.f};
        #pragma unroll 8
        for (int k = 0; k < KSNIP; ++k) {
            float4 va = NA4[k*CH4 + tid];
            float4 vb = NB4[k*CH4 + tid];
            aN.x += va.x; aN.y += va.y; aN.z += va.z; aN.w += va.w;
            bN.x += vb.x; bN.y += vb.y; bN.z += vb.z; bN.w += vb.w;
        }
        const float s = 1.0f/32.0f;
        aN.x *= s; aN.y *= s; aN.z *= s; aN.w *= s;
        bN.x *= s; bN.y *= s; bN.z *= s; bN.w *= s;
        mNA4[tid] = aN; mNB4[tid] = bN;
    }
    __syncthreads();

    // ---- phase 2: stream PA, PB once; means + per-k dots/sumsq/rowsum ----
    {
        const float4 mna = mNA4[tid];
        const float4 mnb = mNB4[tid];
        float4 accA = {0.f,0.f,0.f,0.f}, accB = {0.f,0.f,0.f,0.f};
        for (int k = 0; k < KSNIP; ++k) {
            float4 va = PA4[k*CH4 + tid];
            float4 vb = PB4[k*CH4 + tid];
            accA.x += va.x; accA.y += va.y; accA.z += va.z; accA.w += va.w;
            accB.x += vb.x; accB.y += vb.y; accB.z += vb.z; accB.w += vb.w;
            float pdA = dot4(va, mnb);   // -> dot(meanNB, PA[b,k])
            float psA = dot4(va, va);
            float prA = sum4(va);
            float pdB = dot4(vb, mna);   // -> dot(meanNA, PB[b,k])
            float psB = dot4(vb, vb);
            #pragma unroll
            for (int o = 32; o; o >>= 1) {
                pdA += __shfl_xor(pdA, o);
                psA += __shfl_xor(psA, o);
                prA += __shfl_xor(prA, o);
                pdB += __shfl_xor(pdB, o);
                psB += __shfl_xor(psB, o);
            }
            if (lane == 0) {
                sp[0][k][wave] = pdA;
                sp[1][k][wave] = psA;
                sp[2][k][wave] = prA;
                sp[3][k][wave] = pdB;
                sp[4][k][wave] = psB;
            }
        }
        const float s = 1.0f/32.0f;
        accA.x *= s; accA.y *= s; accA.z *= s; accA.w *= s;
        accB.x *= s; accB.y *= s; accB.z *= s; accB.w *= s;
        mPA4[tid] = accA; mPB4[tid] = accB;
    }
    __syncthreads();

    // ---- combine per-k partials -> ws ----
    if (tid < KSNIP) {
        float r0=0.f, r1=0.f, r2=0.f, r3=0.f, r4=0.f;
        #pragma unroll
        for (int w = 0; w < 8; ++w) {
            r0 += sp[0][tid][w]; r1 += sp[1][tid][w]; r2 += sp[2][tid][w];
            r3 += sp[3][tid][w]; r4 += sp[4][tid][w];
        }
        ws[OFF_DOTNBPA + b*KSNIP + tid] = r0;
        ws[OFF_SQPA    + b*KSNIP + tid] = r1;
        ws[OFF_ACT     + b*KSNIP + tid] = r2 * (1.0f/2048.0f);
        ws[OFF_DOTNAPB + b*KSNIP + tid] = r3;
        ws[OFF_SQPB    + b*KSNIP + tid] = r4;
    }

    // ---- phase 3: per-b scalars from LDS means ----
    {
        float4 a  = mPA4[tid];
        float4 bb = mPB4[tid];
        float4 na = mNA4[tid];
        float4 nb = mNB4[tid];
        float v0 = dot4(a, a);
        float v1 = dot4(bb, bb);
        float v2 = dot4(na, na);
        float v3 = dot4(nb, nb);
        float v4 = dot4(na, a);
        float v5 = dot4(nb, bb);
        #pragma unroll
        for (int o = 32; o; o >>= 1) {
            v0 += __shfl_xor(v0, o);
            v1 += __shfl_xor(v1, o);
            v2 += __shfl_xor(v2, o);
            v3 += __shfl_xor(v3, o);
            v4 += __shfl_xor(v4, o);
            v5 += __shfl_xor(v5, o);
        }
        if (lane == 0) {
            sred[wave][0]=v0; sred[wave][1]=v1; sred[wave][2]=v2;
            sred[wave][3]=v3; sred[wave][4]=v4; sred[wave][5]=v5;
        }
        __syncthreads();
        if (tid == 0) {
            float t0=0.f,t1=0.f,t2=0.f,t3=0.f,t4=0.f,t5=0.f;
            #pragma unroll
            for (int w = 0; w < 8; ++w) {
                t0+=sred[w][0]; t1+=sred[w][1]; t2+=sred[w][2];
                t3+=sred[w][3]; t4+=sred[w][4]; t5+=sred[w][5];
            }
            ws[OFF_N2PA + b] = t0;
            ws[OFF_N2PB + b] = t1;
            ws[OFF_N2NA + b] = t2;
            ws[OFF_N2NB + b] = t3;
            ws[OFF_DAP  + b] = t4;
            ws[OFF_DBP  + b] = t5;
        }
    }
}

// Single block, 256 threads (thread == video b). Finishes all losses.
__global__ __launch_bounds__(256) void finish_kernel(
    const float* __restrict__ vs, const float* __restrict__ label,
    const float* __restrict__ ws, float* __restrict__ out)
{
    const int tid = threadIdx.x;
    const int b   = tid;

    __shared__ float an[BATCH][33];   // +1 pad on 32 -> stride 33, conflict-free
    __shared__ float sbuf[4];
    __shared__ float sred[4][3];
    __shared__ int   s_anchor, s_cnt;

    const float* dotNAPB = ws + OFF_DOTNAPB;
    const float* sqPB    = ws + OFF_SQPB;
    const float* dotNBPA = ws + OFF_DOTNBPA;
    const float* sqPA    = ws + OFF_SQPA;
    const float* act     = ws + OFF_ACT;
    const float* n2PA    = ws + OFF_N2PA;
    const float* n2PB    = ws + OFF_N2PB;
    const float* n2NA    = ws + OFF_N2NA;
    const float* n2NB    = ws + OFF_N2NB;
    const float* dAP     = ws + OFF_DAP;
    const float* dBP     = ws + OFF_DBP;

    const float invT = 1.0f / 0.07f;
    const float nPA = sqrtf(n2PA[b]);
    const float nPB = sqrtf(n2PB[b]);
    const float nNA = sqrtf(n2NA[b]);
    const float nNB = sqrtf(n2NB[b]);

    // NCE 1: q=meanNA, k=meanPA, neg=PB  (online logsumexp over 33 logits)
    float nce;
    {
        float lpos = dAP[b] / (nNA * nPA) * invT;
        float m = lpos, s = 1.0f;
        for (int k = 0; k < KSNIP; ++k) {
            float v = dotNAPB[b*KSNIP + k] / (nNA * sqrtf(sqPB[b*KSNIP + k])) * invT;
            if (v > m) { s = s * expf(m - v) + 1.0f; m = v; }
            else       { s += expf(v - m); }
        }
        nce = (logf(s) + m) - lpos;
    }
    // NCE 2: q=meanNB, k=meanPB, neg=PA
    {
        float lpos = dBP[b] / (nNB * nPB) * invT;
        float m = lpos, s = 1.0f;
        for (int k = 0; k < KSNIP; ++k) {
            float v = dotNBPA[b*KSNIP + k] / (nNB * sqrtf(sqPA[b*KSNIP + k])) * invT;
            if (v > m) { s = s * expf(m - v) + 1.0f; m = v; }
            else       { s += expf(v - m); }
        }
        nce += (logf(s) + m) - lpos;
    }

    // abs loss
    float la   = fmaxf(150.0f - nPA, 0.0f);
    float absb = (la + nPB) * (la + nPB);

    // BCE with row-normalized labels
    float rs = 0.0f;
    for (int c = 0; c < NCLSS; ++c) rs += label[b*NCLSS + c];
    float clsb = 0.0f;
    for (int c = 0; c < NCLSS; ++c) {
        float l = label[b*NCLSS + c] / rs;
        float p = vs[b*NCLSS + c];
        clsb -= l * logf(p) + (1.0f - l) * logf(1.0f - p);
    }

    // block sums (valid on all threads)
    auto blocksum = [&](float v) -> float {
        #pragma unroll
        for (int o = 32; o; o >>= 1) v += __shfl_xor(v, o);
        __syncthreads();
        if ((tid & 63) == 0) sbuf[tid >> 6] = v;
        __syncthreads();
        return sbuf[0] + sbuf[1] + sbuf[2] + sbuf[3];
    };

    const float loss_snico = blocksum(nce)  / 256.0f;
    const float loss_abs   = blocksum(absb) / 256.0f;
    const float loss_cls   = blocksum(clsb) / 5120.0f;

    // ---- triplet ----
    for (int i = tid; i < BATCH*KSNIP; i += BATCH)
        an[i >> 5][i & 31] = act[i];
    __syncthreads();
    {
        float nrm = 0.0f;
        #pragma unroll
        for (int k = 0; k < KSNIP; ++k) { float v = an[b][k]; nrm += v * v; }
        float inv = 1.0f / sqrtf(nrm);
        #pragma unroll
        for (int k = 0; k < KSNIP; ++k) an[b][k] *= inv;
    }

    float trip_total = 0.0f;   // accumulated on thread 0
    for (int c = 0; c < NCLSS; ++c) {
        __syncthreads();   // protects an-normalize (first iter) and s_cnt/sred reuse
        if (tid == 0) { s_anchor = -1; s_cnt = 0; }
        __syncthreads();
        const bool mm = label[b*NCLSS + c] > 0.5f;
        if (mm) { atomicMax(&s_anchor, b); atomicAdd(&s_cnt, 1); }
        __syncthreads();
        const int cnt = s_cnt, anchor = s_anchor;
        if (cnt > 1) {
            float dacc = 0.0f;
            #pragma unroll
            for (int k = 0; k < KSNIP; ++k) dacc += an[anchor][k] * an[b][k];
            const float d = 1.0f - dacc;
            float vAll = d;
            float vMem = (mm && b != anchor) ? d : -__builtin_inff();
            float vNon = (!mm) ? d : __builtin_inff();
            #pragma unroll
            for (int o = 32; o; o >>= 1) {
                vAll = fmaxf(vAll, __shfl_xor(vAll, o));
                vMem = fmaxf(vMem, __shfl_xor(vMem, o));
                vNon = fminf(vNon, __shfl_xor(vNon, o));
            }
            if ((tid & 63) == 0) {
                int w = tid >> 6;
                sred[w][0] = vAll; sred[w][1] = vMem; sred[w][2] = vNon;
            }
            __syncthreads();
            if (tid == 0) {
                float maxAll = fmaxf(fmaxf(sred[0][0], sred[1][0]), fmaxf(sred[2][0], sred[3][0]));
                float maxMem = fmaxf(fmaxf(sred[0][1], sred[1][1]), fmaxf(sred[2][1], sred[3][1]));
                float minNon = fminf(fminf(sred[0][2], sred[1][2]), fminf(sred[2][2], sred[3][2]));
                float max_d = fmaxf(0.0f, maxMem);
                float min_d = fminf(maxAll, minNon);
                trip_total += fmaxf(max_d - min_d + 0.8f, 0.0f);
            }
        }
    }

    if (tid == 0) {
        float total = loss_cls + 0.01f * loss_snico + 0.0005f * loss_abs + 0.005f * trip_total;
        out[0] = total;
        out[1] = loss_cls;
        out[2] = loss_snico;
        out[3] = loss_abs;
        out[4] = trip_total;
    }
}

extern "C" void kernel_launch(void* const* d_in, const int* in_sizes, int n_in,
                              void* d_out, int out_size, void* d_ws, size_t ws_size,
                              hipStream_t stream) {
    const float* vs    = (const float*)d_in[0];
    const float* label = (const float*)d_in[1];
    const float* PA    = (const float*)d_in[2];
    const float* PB    = (const float*)d_in[3];
    const float* NAp   = (const float*)d_in[4];
    const float* NBp   = (const float*)d_in[5];
    float* ws  = (float*)d_ws;
    float* out = (float*)d_out;

    per_video_kernel<<<dim3(BATCH), dim3(512), 0, stream>>>(PA, PB, NAp, NBp, ws);
    finish_kernel<<<dim3(1), dim3(256), 0, stream>>>(vs, label, ws, out);
}